// Round 11
// baseline (6792.934 us; speedup 1.0000x reference)
//
#include <hip/hip_runtime.h>
#include <stdint.h>

#define TT 4096
#define INW 1024
#define HW 1024
#define OUTW 512
#define CH 2048   // HW+IN
#define NREP 8    // mailbox replicas (spread poll load across L3 lines/slices)

// ws layout:
//   [0, NREP*16KB)            : hpair[NREP][2][1024] (uint64: epoch<<32 | float_bits)
//   [NREP*16KB, +16MB)        : h_all float[TT*HW]

__device__ __forceinline__ uint64_t pack_pair(float v, uint32_t ep) {
    return ((uint64_t)ep << 32) | (uint64_t)__float_as_uint(v);
}
__device__ __forceinline__ float sigmoid_fast(float z) {
    return 1.0f / (1.0f + __expf(-z));
}
__device__ __forceinline__ float tanh_fast(float z) {
    return 1.0f - 2.0f / (1.0f + __expf(2.0f * z));
}

// DPP wave64 sum: result lands in lane 63 (other lanes hold partials).
template <int CTRL>
__device__ __forceinline__ float dpp_add(float v) {
    int s = __builtin_amdgcn_update_dpp(0, __float_as_int(v), CTRL, 0xF, 0xF, true);
    return v + __int_as_float(s);
}
__device__ __forceinline__ float wave_sum_to_lane63(float v) {
    v = dpp_add<0x111>(v);  // row_shr:1
    v = dpp_add<0x112>(v);  // row_shr:2
    v = dpp_add<0x114>(v);  // row_shr:4
    v = dpp_add<0x118>(v);  // row_shr:8  -> lane 15/31/47/63 = row sums
    v = dpp_add<0x142>(v);  // row_bcast:15
    v = dpp_add<0x143>(v);  // row_bcast:31 -> lane 63 = total
    return v;
}

__global__ void lstm_init_kernel(uint64_t* __restrict__ hpair) {
    int j = blockIdx.x * blockDim.x + threadIdx.x;  // 0 .. NREP*HW-1
    if (j < NREP * HW) {
        int r = j >> 10, u = j & (HW - 1);
        hpair[(size_t)r * 2 * HW + u]      = pack_pair(0.0f, 0u);          // buf0: h_0, epoch 0
        hpair[(size_t)r * 2 * HW + HW + u] = pack_pair(0.0f, 0x80000000u); // buf1: never-match
    }
}

// 256 blocks x 256 threads (R6-proven topology & pacing). Block b owns hidden
// units 4b..4b+3; wave w owns unit gu=4b+w (all 4 gates), polls pair-quarter
// [256w,256w+256) of REPLICA b&7 (issue-at-need, single round in flight).
// Publish: lane 63 stores the (value,epoch) pair to ALL NREP replicas (8
// independent 8B stores in flight together). Per-L3-line poll load drops 8x.
__global__ __launch_bounds__(256, 1) void lstm_seq_kernel(
    const float* __restrict__ x,
    const float* __restrict__ wf, const float* __restrict__ bf,
    const float* __restrict__ wi, const float* __restrict__ bi,
    const float* __restrict__ wc, const float* __restrict__ bc,
    const float* __restrict__ wo, const float* __restrict__ bo,
    uint64_t* __restrict__ hpair, float* __restrict__ h_all,
    float* __restrict__ out)
{
    __shared__ float hsh[2][HW];  // 8KB double-buffered h state

    const int tid  = threadIdx.x;
    const int lane = tid & 63;
    const int w    = tid >> 6;            // wave 0..3
    const int b    = blockIdx.x;          // 0..255
    const int gu   = b * 4 + w;           // owned hidden unit
    const int rep  = b & (NREP - 1);      // which replica this block polls
    uint64_t* __restrict__ myrep = hpair + (size_t)rep * 2 * HW;

    // ---- own-quarter-first column permutation: slot s -> column k ----
    int kmap[16];
#pragma unroll
    for (int s = 0; s < 4; ++s) kmap[s] = 4 * w + s;
#pragma unroll
    for (int s = 4; s < 16; ++s) kmap[s] = 4 * ((w + 1 + ((s - 4) >> 2)) & 3) + (s & 3);

    // ---- one-time: weights into registers (coalesced within each k-column) --
    float wh[64], wx[64];  // wh[g*16+s] = W_g[gu][lane + 64*kmap[s]]; wx natural
    {
        const float* wptr[4] = {wf, wi, wc, wo};
#pragma unroll
        for (int g = 0; g < 4; ++g) {
            const float* base = wptr[g] + (size_t)gu * CH + lane;
#pragma unroll
            for (int s = 0; s < 16; ++s) wh[g * 16 + s] = base[(size_t)kmap[s] * 64];
#pragma unroll
            for (int k = 0; k < 16; ++k) wx[g * 16 + k] = base[1024 + (size_t)k * 64];
        }
    }
#pragma unroll
    for (int i = 0; i < 64; ++i) {
        asm volatile("" : "+v"(wh[i]));
        asm volatile("" : "+v"(wx[i]));
    }

    const float bias0 = bf[gu];
    const float bias1 = bi[gu];
    const float bias2 = bc[gu];
    const float bias3 = bo[gu];

    // ---- prologue: x_0 load + its partial sums (bias seeded on lane 63) ----
    float xacc0 = (lane == 63) ? bias0 : 0.f;
    float xacc1 = (lane == 63) ? bias1 : 0.f;
    float xacc2 = (lane == 63) ? bias2 : 0.f;
    float xacc3 = (lane == 63) ? bias3 : 0.f;
    {
        const float* xp = x + lane;
        float xv[16];
#pragma unroll
        for (int k = 0; k < 16; ++k) xv[k] = xp[(size_t)k * 64];
#pragma unroll
        for (int k = 0; k < 16; ++k) {
            xacc0 = fmaf(wx[0 * 16 + k], xv[k], xacc0);
            xacc1 = fmaf(wx[1 * 16 + k], xv[k], xacc1);
            xacc2 = fmaf(wx[2 * 16 + k], xv[k], xacc2);
            xacc3 = fmaf(wx[3 * 16 + k], xv[k], xacc3);
        }
    }

    float c = 0.0f, h_last = 0.0f;  // meaningful on lane 63

    for (int t = 0; t < TT; ++t) {
        const int p = t & 1;

        // ---- 1. poll my quarter of MY replica (single round in flight) ----
        const uint64_t* hp = myrep + (size_t)p * HW + 256 * w + lane;
        float hq[4];
        {
            bool ok;
            do {
                uint64_t pv[4];
#pragma unroll
                for (int k = 0; k < 4; ++k)
                    pv[k] = __hip_atomic_load(&hp[64 * k],
                                              __ATOMIC_RELAXED, __HIP_MEMORY_SCOPE_SYSTEM);
                ok = true;
#pragma unroll
                for (int k = 0; k < 4; ++k)
                    ok &= ((uint32_t)(pv[k] >> 32) == (uint32_t)t);
#pragma unroll
                for (int k = 0; k < 4; ++k)
                    hq[k] = __uint_as_float((uint32_t)pv[k]);
            } while (!__all(ok));
        }

        // ---- 2. LDS share + pre-barrier own-quarter FMA ----
#pragma unroll
        for (int k = 0; k < 4; ++k)
            hsh[p][256 * w + lane + 64 * k] = hq[k];

        float acc0 = xacc0, acc1 = xacc1, acc2 = xacc2, acc3 = xacc3;
#pragma unroll
        for (int j = 0; j < 4; ++j) {
            acc0 = fmaf(wh[0 * 16 + j], hq[j], acc0);
            acc1 = fmaf(wh[1 * 16 + j], hq[j], acc1);
            acc2 = fmaf(wh[2 * 16 + j], hq[j], acc2);
            acc3 = fmaf(wh[3 * 16 + j], hq[j], acc3);
        }
        __syncthreads();
        // (Reuse safety per replica: any unit publishing t+2 first detected
        //  t+1 on its replica, which requires ALL units' t+1 publishes, which
        //  requires every block to have passed step t's barrier -> done reading
        //  epoch-t data in every replica. Double-buffer + induction.)

        // ---- 3. prefetch x_{t+1} AFTER the barrier ----
        float xn[16];
        {
            const int tn = (t + 1 < TT) ? t + 1 : t;
            const float* xp = x + (size_t)tn * INW + lane;
#pragma unroll
            for (int k = 0; k < 16; ++k) xn[k] = xp[(size_t)k * 64];
        }

        // ---- 4. coalesced h_all write: hsh[p] = state entering t -> row t-1
        if (t >= 1 && b == (t & 255)) {
            float4 hv4 = *(const float4*)&hsh[p][tid * 4];
            *(float4*)(h_all + (size_t)(t - 1) * HW + tid * 4) = hv4;
        }

        // ---- 5. h part: remaining 3 quarters (static wh slots 4..15) ----
#pragma unroll
        for (int i = 0; i < 3; ++i) {
            const int q = (w + 1 + i) & 3;                 // wave-uniform
            const float* hrow = &hsh[p][256 * q + lane];
#pragma unroll
            for (int j = 0; j < 4; ++j) {
                const float v = hrow[64 * j];
                const int s = 4 + i * 4 + j;               // static index
                acc0 = fmaf(wh[0 * 16 + s], v, acc0);
                acc1 = fmaf(wh[1 * 16 + s], v, acc1);
                acc2 = fmaf(wh[2 * 16 + s], v, acc2);
                acc3 = fmaf(wh[3 * 16 + s], v, acc3);
            }
        }

        // ---- 6. DPP reduce to lane 63 ----
        acc0 = wave_sum_to_lane63(acc0);
        acc1 = wave_sum_to_lane63(acc1);
        acc2 = wave_sum_to_lane63(acc2);
        acc3 = wave_sum_to_lane63(acc3);

        // ---- 7. lane 63: activations + publish epoch t+1 to ALL replicas ----
        if (lane == 63) {
            float f  = sigmoid_fast(acc0);
            float ii = sigmoid_fast(acc1);
            float g  = tanh_fast(acc2);
            float o  = sigmoid_fast(acc3);
            c = fmaf(f, c, ii * g);
            float hn = o * tanh_fast(c);
            h_last = hn;
            const uint64_t pk = pack_pair(hn, (uint32_t)(t + 1));
            uint64_t* dst = hpair + (size_t)((t + 1) & 1) * HW + gu;
#pragma unroll
            for (int r = 0; r < NREP; ++r)
                __hip_atomic_store(dst + (size_t)r * 2 * HW, pk,
                                   __ATOMIC_RELAXED, __HIP_MEMORY_SCOPE_SYSTEM);
        }
        __builtin_amdgcn_sched_barrier(0);  // keep xacc recompute below publish

        // ---- 8. post-publish (slack window): x partials for t+1 + bias seed --
        float nx0 = (lane == 63) ? bias0 : 0.f;
        float nx1 = (lane == 63) ? bias1 : 0.f;
        float nx2 = (lane == 63) ? bias2 : 0.f;
        float nx3 = (lane == 63) ? bias3 : 0.f;
#pragma unroll
        for (int k = 0; k < 16; ++k) {
            nx0 = fmaf(wx[0 * 16 + k], xn[k], nx0);
            nx1 = fmaf(wx[1 * 16 + k], xn[k], nx1);
            nx2 = fmaf(wx[2 * 16 + k], xn[k], nx2);
            nx3 = fmaf(wx[3 * 16 + k], xn[k], nx3);
        }
        xacc0 = nx0; xacc1 = nx1; xacc2 = nx2; xacc3 = nx3;
    }

    if (lane == 63) {
        // final h_all row (epoch TT is never polled by anyone)
        h_all[(size_t)(TT - 1) * HW + gu] = h_last;
        out[(size_t)TT * OUTW + gu]      = h_last;
        out[(size_t)TT * OUTW + HW + gu] = c;
    }
}

// ys[t][o] = sum_k h_all[t][k] * why[o][k] + by[o]
// grid (TT/64, OUTW/64) = (64, 8); block 256; 64x64 tile, 4x4 per thread.
__global__ __launch_bounds__(256) void lstm_ygemm_kernel(
    const float* __restrict__ hall, const float* __restrict__ why,
    const float* __restrict__ by, float* __restrict__ ys)
{
    __shared__ float hs[64][17];
    __shared__ float wsm[64][17];
    const int t0 = blockIdx.x * 64, o0 = blockIdx.y * 64;
    const int tid = threadIdx.x;
    const int tx = tid & 15, ty = tid >> 4;

    float acc[4][4] = {};
    const int r = tid >> 2;            // 0..63
    const int cc = (tid & 3) * 4;      // 0,4,8,12

    for (int kk = 0; kk < HW; kk += 16) {
        float4 hv = *(const float4*)(hall + (size_t)(t0 + r) * HW + kk + cc);
        hs[r][cc + 0] = hv.x; hs[r][cc + 1] = hv.y;
        hs[r][cc + 2] = hv.z; hs[r][cc + 3] = hv.w;
        float4 wv = *(const float4*)(why + (size_t)(o0 + r) * HW + kk + cc);
        wsm[r][cc + 0] = wv.x; wsm[r][cc + 1] = wv.y;
        wsm[r][cc + 2] = wv.z; wsm[r][cc + 3] = wv.w;
        __syncthreads();
#pragma unroll
        for (int k = 0; k < 16; ++k) {
            float ha[4], wa[4];
#pragma unroll
            for (int i = 0; i < 4; ++i) ha[i] = hs[ty * 4 + i][k];
#pragma unroll
            for (int j = 0; j < 4; ++j) wa[j] = wsm[tx * 4 + j][k];
#pragma unroll
            for (int i = 0; i < 4; ++i)
#pragma unroll
                for (int j = 0; j < 4; ++j)
                    acc[i][j] = fmaf(ha[i], wa[j], acc[i][j]);
        }
        __syncthreads();
    }
#pragma unroll
    for (int i = 0; i < 4; ++i) {
#pragma unroll
        for (int j = 0; j < 4; ++j) {
            int oo = o0 + tx * 4 + j;
            ys[(size_t)(t0 + ty * 4 + i) * OUTW + oo] = acc[i][j] + by[oo];
        }
    }
}

extern "C" void kernel_launch(void* const* d_in, const int* in_sizes, int n_in,
                              void* d_out, int out_size, void* d_ws, size_t ws_size,
                              hipStream_t stream) {
    const float* x   = (const float*)d_in[0];
    const float* wf  = (const float*)d_in[1];
    const float* bf  = (const float*)d_in[2];
    const float* wi  = (const float*)d_in[3];
    const float* bi  = (const float*)d_in[4];
    const float* wc  = (const float*)d_in[5];
    const float* bc  = (const float*)d_in[6];
    const float* wo  = (const float*)d_in[7];
    const float* bo  = (const float*)d_in[8];
    const float* why = (const float*)d_in[9];
    const float* by  = (const float*)d_in[10];
    float* out = (float*)d_out;

    uint64_t* hpair = (uint64_t*)d_ws;
    float* h_all = (float*)((char*)d_ws + (size_t)NREP * 2 * HW * sizeof(uint64_t));

    lstm_init_kernel<<<dim3(NREP * HW / 256), dim3(256), 0, stream>>>(hpair);
    lstm_seq_kernel<<<dim3(256), dim3(256), 0, stream>>>(
        x, wf, bf, wi, bi, wc, bc, wo, bo, hpair, h_all, out);
    lstm_ygemm_kernel<<<dim3(64, 8), dim3(256), 0, stream>>>(h_all, why, by, out);
}

// Round 12
// 6586.132 us; speedup vs baseline: 1.0314x; 1.0314x over previous
//
#include <hip/hip_runtime.h>
#include <stdint.h>

#define TT 4096
#define INW 1024
#define HW 1024
#define OUTW 512
#define CH 2048   // HW+IN

// ws layout: [0, 16KB) : hpair[2][1024]  (uint64: epoch<<32 | float_bits)

__device__ __forceinline__ uint64_t pack_pair(float v, uint32_t ep) {
    return ((uint64_t)ep << 32) | (uint64_t)__float_as_uint(v);
}
__device__ __forceinline__ float sigmoid_fast(float z) {
    return 1.0f / (1.0f + __expf(-z));
}
__device__ __forceinline__ float tanh_fast(float z) {
    return 1.0f - 2.0f / (1.0f + __expf(2.0f * z));
}

// DPP wave64 sum: result lands in lane 63 (other lanes hold partials).
template <int CTRL>
__device__ __forceinline__ float dpp_add(float v) {
    int s = __builtin_amdgcn_update_dpp(0, __float_as_int(v), CTRL, 0xF, 0xF, true);
    return v + __int_as_float(s);
}
__device__ __forceinline__ float wave_sum_to_lane63(float v) {
    v = dpp_add<0x111>(v);  // row_shr:1
    v = dpp_add<0x112>(v);  // row_shr:2
    v = dpp_add<0x114>(v);  // row_shr:4
    v = dpp_add<0x118>(v);  // row_shr:8  -> lane 15/31/47/63 = row sums
    v = dpp_add<0x142>(v);  // row_bcast:15
    v = dpp_add<0x143>(v);  // row_bcast:31 -> lane 63 = total
    return v;
}

__global__ void lstm_init_kernel(uint64_t* __restrict__ hpair) {
    int j = blockIdx.x * blockDim.x + threadIdx.x;
    if (j < HW) {
        hpair[j]      = pack_pair(0.0f, 0u);          // buf0: h_0 = 0, epoch 0
        hpair[HW + j] = pack_pair(0.0f, 0x80000000u); // buf1: never-matching epoch
    }
}

// 256 blocks x 256 threads (R6-proven topology & pacing — the measured latency
// floor: ~1.64us/step, insensitive to poll rate/fan-out/publisher count).
// Block b owns hidden units 4b..4b+3; wave w owns unit gu=4b+w.
// NEW vs R10: ys is FUSED — at iteration t, hsh[p]=H_t, so waves 0/1 compute
// ys[t-1][2b+w] = why[2b+w].H_t + by in the post-publish slack window
// (R10 proved the slack absorbs extra work for free). No h_all, no ygemm.
__global__ __launch_bounds__(256, 1) void lstm_seq_kernel(
    const float* __restrict__ x,
    const float* __restrict__ wf, const float* __restrict__ bf,
    const float* __restrict__ wi, const float* __restrict__ bi,
    const float* __restrict__ wc, const float* __restrict__ bc,
    const float* __restrict__ wo, const float* __restrict__ bo,
    const float* __restrict__ why, const float* __restrict__ by,
    uint64_t* __restrict__ hpair, float* __restrict__ out)
{
    __shared__ float hsh[2][HW];  // 8KB double-buffered h state

    const int tid  = threadIdx.x;
    const int lane = tid & 63;
    const int w    = tid >> 6;            // wave 0..3
    const int b    = blockIdx.x;          // 0..255
    const int gu   = b * 4 + w;           // owned hidden unit

    // ---- own-quarter-first column permutation: slot s -> column k ----
    int kmap[16];
#pragma unroll
    for (int s = 0; s < 4; ++s) kmap[s] = 4 * w + s;
#pragma unroll
    for (int s = 4; s < 16; ++s) kmap[s] = 4 * ((w + 1 + ((s - 4) >> 2)) & 3) + (s & 3);

    // ---- one-time: weights into registers (coalesced within each k-column) --
    float wh[64], wx[64];  // wh[g*16+s] = W_g[gu][lane + 64*kmap[s]]; wx natural
    {
        const float* wptr[4] = {wf, wi, wc, wo};
#pragma unroll
        for (int g = 0; g < 4; ++g) {
            const float* base = wptr[g] + (size_t)gu * CH + lane;
#pragma unroll
            for (int s = 0; s < 16; ++s) wh[g * 16 + s] = base[(size_t)kmap[s] * 64];
#pragma unroll
            for (int k = 0; k < 16; ++k) wx[g * 16 + k] = base[1024 + (size_t)k * 64];
        }
    }
#pragma unroll
    for (int i = 0; i < 64; ++i) {
        asm volatile("" : "+v"(wh[i]));
        asm volatile("" : "+v"(wx[i]));
    }

    // ---- ys fusion state: waves 0/1 own output row yo = 2b+w ----
    const int yo = 2 * b + w;             // valid for w<2
    float wy[16];
    float ybias = 0.f;
    if (w < 2) {
        const float* yb = why + (size_t)yo * HW + lane;
#pragma unroll
        for (int k = 0; k < 16; ++k) wy[k] = yb[(size_t)k * 64];
        ybias = by[yo];
    } else {
#pragma unroll
        for (int k = 0; k < 16; ++k) wy[k] = 0.f;
    }
#pragma unroll
    for (int i = 0; i < 16; ++i)
        asm volatile("" : "+v"(wy[i]));

    const float bias0 = bf[gu];
    const float bias1 = bi[gu];
    const float bias2 = bc[gu];
    const float bias3 = bo[gu];

    // ---- prologue: x_0 load + its partial sums (bias seeded on lane 63) ----
    float xacc0 = (lane == 63) ? bias0 : 0.f;
    float xacc1 = (lane == 63) ? bias1 : 0.f;
    float xacc2 = (lane == 63) ? bias2 : 0.f;
    float xacc3 = (lane == 63) ? bias3 : 0.f;
    {
        const float* xp = x + lane;
        float xv[16];
#pragma unroll
        for (int k = 0; k < 16; ++k) xv[k] = xp[(size_t)k * 64];
#pragma unroll
        for (int k = 0; k < 16; ++k) {
            xacc0 = fmaf(wx[0 * 16 + k], xv[k], xacc0);
            xacc1 = fmaf(wx[1 * 16 + k], xv[k], xacc1);
            xacc2 = fmaf(wx[2 * 16 + k], xv[k], xacc2);
            xacc3 = fmaf(wx[3 * 16 + k], xv[k], xacc3);
        }
    }

    float c = 0.0f, h_last = 0.0f;  // meaningful on lane 63

    for (int t = 0; t < TT; ++t) {
        const int p = t & 1;

        // ---- 1. poll my quarter (R6 pacing: single round in flight) ----
        const uint64_t* hp = hpair + (size_t)p * HW + 256 * w + lane;
        float hq[4];
        {
            bool ok;
            do {
                uint64_t pv[4];
#pragma unroll
                for (int k = 0; k < 4; ++k)
                    pv[k] = __hip_atomic_load(&hp[64 * k],
                                              __ATOMIC_RELAXED, __HIP_MEMORY_SCOPE_SYSTEM);
                ok = true;
#pragma unroll
                for (int k = 0; k < 4; ++k)
                    ok &= ((uint32_t)(pv[k] >> 32) == (uint32_t)t);
#pragma unroll
                for (int k = 0; k < 4; ++k)
                    hq[k] = __uint_as_float((uint32_t)pv[k]);
            } while (!__all(ok));
        }

        // ---- 2. LDS share + pre-barrier own-quarter FMA ----
#pragma unroll
        for (int k = 0; k < 4; ++k)
            hsh[p][256 * w + lane + 64 * k] = hq[k];

        float acc0 = xacc0, acc1 = xacc1, acc2 = xacc2, acc3 = xacc3;
#pragma unroll
        for (int j = 0; j < 4; ++j) {
            acc0 = fmaf(wh[0 * 16 + j], hq[j], acc0);
            acc1 = fmaf(wh[1 * 16 + j], hq[j], acc1);
            acc2 = fmaf(wh[2 * 16 + j], hq[j], acc2);
            acc3 = fmaf(wh[3 * 16 + j], hq[j], acc3);
        }
        __syncthreads();
        // (no 2nd barrier: hsh[p]/hpair[p] are next written at t+2; detecting
        //  epoch t+2 transitively proves every block finished step t's reads.)

        // ---- 3. prefetch x_{t+1} AFTER the barrier ----
        float xn[16];
        {
            const int tn = (t + 1 < TT) ? t + 1 : t;
            const float* xp = x + (size_t)tn * INW + lane;
#pragma unroll
            for (int k = 0; k < 16; ++k) xn[k] = xp[(size_t)k * 64];
        }

        // ---- 4. h part: remaining 3 quarters (static wh slots 4..15) ----
#pragma unroll
        for (int i = 0; i < 3; ++i) {
            const int q = (w + 1 + i) & 3;                 // wave-uniform
            const float* hrow = &hsh[p][256 * q + lane];
#pragma unroll
            for (int j = 0; j < 4; ++j) {
                const float v = hrow[64 * j];
                const int s = 4 + i * 4 + j;               // static index
                acc0 = fmaf(wh[0 * 16 + s], v, acc0);
                acc1 = fmaf(wh[1 * 16 + s], v, acc1);
                acc2 = fmaf(wh[2 * 16 + s], v, acc2);
                acc3 = fmaf(wh[3 * 16 + s], v, acc3);
            }
        }

        // ---- 5. DPP reduce to lane 63 ----
        acc0 = wave_sum_to_lane63(acc0);
        acc1 = wave_sum_to_lane63(acc1);
        acc2 = wave_sum_to_lane63(acc2);
        acc3 = wave_sum_to_lane63(acc3);

        // ---- 6. lane 63: activations + publish epoch t+1 ----
        if (lane == 63) {
            float f  = sigmoid_fast(acc0);
            float ii = sigmoid_fast(acc1);
            float g  = tanh_fast(acc2);
            float o  = sigmoid_fast(acc3);
            c = fmaf(f, c, ii * g);
            float hn = o * tanh_fast(c);
            h_last = hn;
            __hip_atomic_store(&hpair[(size_t)((t + 1) & 1) * HW + gu],
                               pack_pair(hn, (uint32_t)(t + 1)),
                               __ATOMIC_RELAXED, __HIP_MEMORY_SCOPE_SYSTEM);
        }
        __builtin_amdgcn_sched_barrier(0);  // keep slack work below the publish

        // ---- 7. slack: fused ys[t-1][yo] = why[yo].H_t + by[yo]  (waves 0/1)
        if (w < 2 && t >= 1) {
            float yacc = (lane == 63) ? ybias : 0.f;
#pragma unroll
            for (int k = 0; k < 16; ++k)
                yacc = fmaf(wy[k], hsh[p][lane + 64 * k], yacc);
            yacc = wave_sum_to_lane63(yacc);
            if (lane == 63)
                out[(size_t)(t - 1) * OUTW + yo] = yacc;
        }

        // ---- 8. slack: x partials for t+1 + bias seed ----
        float nx0 = (lane == 63) ? bias0 : 0.f;
        float nx1 = (lane == 63) ? bias1 : 0.f;
        float nx2 = (lane == 63) ? bias2 : 0.f;
        float nx3 = (lane == 63) ? bias3 : 0.f;
#pragma unroll
        for (int k = 0; k < 16; ++k) {
            nx0 = fmaf(wx[0 * 16 + k], xn[k], nx0);
            nx1 = fmaf(wx[1 * 16 + k], xn[k], nx1);
            nx2 = fmaf(wx[2 * 16 + k], xn[k], nx2);
            nx3 = fmaf(wx[3 * 16 + k], xn[k], nx3);
        }
        xacc0 = nx0; xacc1 = nx1; xacc2 = nx2; xacc3 = nx3;
    }

    // ---- epilogue: poll epoch TT (= H_TT) and emit ys[TT-1] ----
    {
        const int p = TT & 1;  // 0
        const uint64_t* hp = hpair + (size_t)p * HW + 256 * w + lane;
        float hq[4];
        bool ok;
        do {
            uint64_t pv[4];
#pragma unroll
            for (int k = 0; k < 4; ++k)
                pv[k] = __hip_atomic_load(&hp[64 * k],
                                          __ATOMIC_RELAXED, __HIP_MEMORY_SCOPE_SYSTEM);
            ok = true;
#pragma unroll
            for (int k = 0; k < 4; ++k)
                ok &= ((uint32_t)(pv[k] >> 32) == (uint32_t)TT);
#pragma unroll
            for (int k = 0; k < 4; ++k)
                hq[k] = __uint_as_float((uint32_t)pv[k]);
        } while (!__all(ok));
#pragma unroll
        for (int k = 0; k < 4; ++k)
            hsh[p][256 * w + lane + 64 * k] = hq[k];
        __syncthreads();
        if (w < 2) {
            float yacc = (lane == 63) ? ybias : 0.f;
#pragma unroll
            for (int k = 0; k < 16; ++k)
                yacc = fmaf(wy[k], hsh[p][lane + 64 * k], yacc);
            yacc = wave_sum_to_lane63(yacc);
            if (lane == 63)
                out[(size_t)(TT - 1) * OUTW + yo] = yacc;
        }
    }

    if (lane == 63) {
        out[(size_t)TT * OUTW + gu]      = h_last;
        out[(size_t)TT * OUTW + HW + gu] = c;
    }
}

extern "C" void kernel_launch(void* const* d_in, const int* in_sizes, int n_in,
                              void* d_out, int out_size, void* d_ws, size_t ws_size,
                              hipStream_t stream) {
    const float* x   = (const float*)d_in[0];
    const float* wf  = (const float*)d_in[1];
    const float* bf  = (const float*)d_in[2];
    const float* wi  = (const float*)d_in[3];
    const float* bi  = (const float*)d_in[4];
    const float* wc  = (const float*)d_in[5];
    const float* bc  = (const float*)d_in[6];
    const float* wo  = (const float*)d_in[7];
    const float* bo  = (const float*)d_in[8];
    const float* why = (const float*)d_in[9];
    const float* by  = (const float*)d_in[10];
    float* out = (float*)d_out;

    uint64_t* hpair = (uint64_t*)d_ws;

    lstm_init_kernel<<<dim3(4), dim3(256), 0, stream>>>(hpair);
    lstm_seq_kernel<<<dim3(256), dim3(256), 0, stream>>>(
        x, wf, bf, wi, bi, wc, bc, wo, bo, why, by, hpair, out);
}